// Round 6
// baseline (2943.339 us; speedup 1.0000x reference)
//
#include <hip/hip_runtime.h>
#include <hip/hip_bf16.h>
#include <cstdint>

#define B_  8
#define T_  16
#define HIN 640
#define WIN 480
#define HP  320
#define WP  240
#define HO  318
#define WO  238

typedef unsigned short u16;
typedef unsigned int   u32;
typedef __attribute__((ext_vector_type(8))) short bf16x8;
typedef __attribute__((ext_vector_type(4))) float f32x4;

#define NFRAG 25    // 20 hi (q0..4 x nt0..3) + 5 lo (nt=2 only, q0..4)
#define TROWS 20    // rows per y-tile
#define LROWS 22    // x LDS rows
#define LCOLS 66    // x LDS cols
#define NBLK  512   // total blocks (2 per CU, co-resident by construction)

__device__ __forceinline__ u16 f2bf(float f) {          // RNE float->bf16 bits
    u32 u = __float_as_uint(f);
    return (u16)((u + 0x7fffu + ((u >> 16) & 1u)) >> 16);
}
__device__ __forceinline__ float bf2f(u16 u) {
    return __uint_as_float(((u32)u) << 16);
}
__device__ __forceinline__ float hsg(float v) {
    return fminf(fmaxf(fmaf(v, 0.2f, 0.5f), 0.0f), 1.0f);
}
// tanh = 1 - 2/(e^{2x}+1): exp(+inf)->1, exp(0)->-1, no clamp needed (6 insts)
__device__ __forceinline__ float tanh_fast(float x) {
    float e = __expf(2.0f * x);
    return 1.0f - __fdividef(2.0f, e + 1.0f);
}

// ---------------- MaxPool (1,2,2) -> bf16 ----------------
__global__ void pool_kernel(const float* __restrict__ in, u32* __restrict__ out) {
    int idx = blockIdx.x * 256 + threadIdx.x;
    const int total = B_ * T_ * HP * (WP / 2);
    if (idx >= total) return;
    int xp   = idx % (WP / 2);
    int rest = idx / (WP / 2);
    int y    = rest % HP;
    int bt   = rest / HP;
    const float* src = in + ((size_t)bt * HIN + 2 * y) * WIN + xp * 4;
    float4 a = *(const float4*)src;
    float4 b = *(const float4*)(src + WIN);
    float m0 = fmaxf(fmaxf(a.x, a.y), fmaxf(b.x, b.y));
    float m1 = fmaxf(fmaxf(a.z, a.w), fmaxf(b.z, b.w));
    out[((size_t)bt * HP + y) * (WP / 2) + xp] = (u32)f2bf(m0) | ((u32)f2bf(m1) << 16);
}

// ---------------- weight fragment pre-pack ----------------
// K layout: k = tap*16+ci (k<144 recurrent), k = 144+xtap (k<153 input conv), else 0.
// Frags 0..19: hi plane, f = q*4+nt. Frags 20..24: lo plane of nt=2 (z_c gate), f = 20+q.
// B-frag (16x16x32): lane l holds W[k = q*32 + (l>>4)*8 + j][n = nt*16 + (l&15)], j=0..7.
__global__ void frag_build(const float* __restrict__ krec, const float* __restrict__ kin,
                           int4* __restrict__ fragbuf) {
    int idx = blockIdx.x * 256 + threadIdx.x;
    if (idx >= NFRAG * 64) return;
    int l = idx & 63, f = idx >> 6;
    int lo = (f >= 20);
    int q  = lo ? (f - 20) : (f >> 2);
    int nt = lo ? 2 : (f & 3);
    int n = nt * 16 + (l & 15), o = l >> 4;
    u16 u[8];
    #pragma unroll
    for (int j = 0; j < 8; ++j) {
        int k = q * 32 + o * 8 + j;
        float wv = 0.0f;
        if (k < 144) wv = krec[k * 64 + n];
        else if (k < 153) wv = kin[(k - 144) * 64 + n];
        u16 hi = f2bf(wv);
        u[j] = lo ? f2bf(wv - bf2f(hi)) : hi;
    }
    int4 v;
    v.x = (int)((u32)u[0] | ((u32)u[1] << 16));
    v.y = (int)((u32)u[2] | ((u32)u[3] << 16));
    v.z = (int)((u32)u[4] | ((u32)u[5] << 16));
    v.w = (int)((u32)u[6] | ((u32)u[7] << 16));
    fragbuf[f * 64 + l] = v;
}

// ---------------- device-scope grid barrier (monotone counter) ----------------
__device__ __forceinline__ void grid_barrier(u32* bar, u32 tgt, int tid) {
    __threadfence();             // release: this block's h stores visible device-wide
    __syncthreads();
    if (tid == 0) {
        atomicAdd(bar, 1u);      // device-scope by default
        while (__hip_atomic_load(bar, __ATOMIC_RELAXED, __HIP_MEMORY_SCOPE_AGENT) < tgt)
            __builtin_amdgcn_s_sleep(2);
    }
    __syncthreads();
    __threadfence();             // acquire: discard stale cached h
}

// ---------------- persistent ConvLSTM (all 16 steps, c in registers) ----------------
// Grid (4,16,8) = 512 blocks = 2/CU (VGPR<=256 via launch_bounds => 8 waves/CU).
// Block tile: 64 x-px x 20 rows. A-fragments read directly from global h (L2-hot).
__global__ __launch_bounds__(256, 2)
void lstm_persist(const u16* __restrict__ xpb,
                  u16* __restrict__ hg0, u16* __restrict__ hg1,
                  const int4* __restrict__ fragbuf,
                  const float* __restrict__ bias,
                  u32* __restrict__ bar) {
    __shared__ __align__(16) u16 sh_B[NFRAG * 64 * 8];   // 25,600 B
    __shared__ u16 sxr[2][LROWS * LCOLS];                //  5,808 B (total 31,408)

    const int tid = threadIdx.x;
    const int wv_ = tid >> 6;
    const int l   = tid & 63;
    const int x0  = blockIdx.x * 64;
    const int y0  = blockIdx.y * TROWS;
    const int b   = blockIdx.z;
    const int o   = l >> 4;
    const int ci0 = (o & 1) * 8;
    const int wx  = wv_ * 16 + (l & 15);
    const int ch  = l & 15;
    const size_t bb = (size_t)b * HO * WO * 16;

    for (int i = tid; i < NFRAG * 64; i += 256)
        ((int4*)sh_B)[i] = fragbuf[i];
    {
        const u16* xs = xpb + (size_t)(b * T_ + 0) * HP * WP;
        for (int i = tid; i < LROWS * LCOLS; i += 256) {
            int ry = i / LCOLS, rx = i % LCOLS;
            int gy = y0 + ry, gx = x0 + rx;
            sxr[0][i] = (gy < HP && gx < WP) ? xs[(size_t)gy * WP + gx] : (u16)0;
        }
    }
    float bv[4];
    #pragma unroll
    for (int nt = 0; nt < 4; ++nt) bv[nt] = bias[nt * 16 + ch];

    float c_reg[5][4][4];
    #pragma unroll
    for (int g = 0; g < 5; ++g)
        #pragma unroll
        for (int m = 0; m < 4; ++m)
            #pragma unroll
            for (int r = 0; r < 4; ++r) c_reg[g][m][r] = 0.0f;

    __syncthreads();

    #pragma unroll 1
    for (int t = 0; t < T_; ++t) {
        u16*       hw = ((t & 1) ? hg1 : hg0) + bb;   // write h_t
        const u16* hr = ((t & 1) ? hg0 : hg1) + bb;   // read h_{t-1} (valid for t>0)
        const u16* sx = sxr[t & 1];

        #pragma unroll
        for (int g = 0; g < 5; ++g) {
            f32x4 acc[4][4];
            #pragma unroll
            for (int m = 0; m < 4; ++m)
                #pragma unroll
                for (int nt = 0; nt < 4; ++nt)
                    acc[m][nt] = (f32x4){bv[nt], bv[nt], bv[nt], bv[nt]};
            const int yb = y0 + 4 * g;

            if (t > 0) {
                // chunks 0..3: recurrent taps 0..7 (tap = 2q + lane-half)
                #pragma unroll 1
                for (int q = 0; q < 4; ++q) {
                    bf16x8 Bh0 = *(const bf16x8*)&sh_B[((q * 4 + 0) * 64 + l) * 8];
                    bf16x8 Bh1 = *(const bf16x8*)&sh_B[((q * 4 + 1) * 64 + l) * 8];
                    bf16x8 Bh2 = *(const bf16x8*)&sh_B[((q * 4 + 2) * 64 + l) * 8];
                    bf16x8 Bh3 = *(const bf16x8*)&sh_B[((q * 4 + 3) * 64 + l) * 8];
                    bf16x8 Bl2 = *(const bf16x8*)&sh_B[((20 + q) * 64 + l) * 8];
                    const int tap = 2 * q + (o >= 2 ? 1 : 0);
                    const int dy = tap / 3, dx = tap - 3 * dy;
                    #pragma unroll
                    for (int m = 0; m < 4; ++m) {
                        const int gy = yb + m + dy - 1;
                        const int gx = x0 + wx + dx - 1;
                        bf16x8 Ah = __builtin_bit_cast(bf16x8, make_int4(0, 0, 0, 0));
                        if ((u32)gy < (u32)HO && (u32)gx < (u32)WO)
                            Ah = *(const bf16x8*)&hr[((size_t)gy * WO + gx) * 16 + ci0];
                        acc[m][0] = __builtin_amdgcn_mfma_f32_16x16x32_bf16(Ah, Bh0, acc[m][0], 0, 0, 0);
                        acc[m][1] = __builtin_amdgcn_mfma_f32_16x16x32_bf16(Ah, Bh1, acc[m][1], 0, 0, 0);
                        acc[m][2] = __builtin_amdgcn_mfma_f32_16x16x32_bf16(Ah, Bh2, acc[m][2], 0, 0, 0);
                        acc[m][2] = __builtin_amdgcn_mfma_f32_16x16x32_bf16(Ah, Bl2, acc[m][2], 0, 0, 0);
                        acc[m][3] = __builtin_amdgcn_mfma_f32_16x16x32_bf16(Ah, Bh3, acc[m][3], 0, 0, 0);
                    }
                }
            }
            // chunk 4: o=0,1 -> rec tap8 (zero at t=0); o=2 -> x taps 0..7; o=3 -> x tap8
            {
                bf16x8 Bh0 = *(const bf16x8*)&sh_B[((16 + 0) * 64 + l) * 8];
                bf16x8 Bh1 = *(const bf16x8*)&sh_B[((16 + 1) * 64 + l) * 8];
                bf16x8 Bh2 = *(const bf16x8*)&sh_B[((16 + 2) * 64 + l) * 8];
                bf16x8 Bh3 = *(const bf16x8*)&sh_B[((16 + 3) * 64 + l) * 8];
                bf16x8 Bl2 = *(const bf16x8*)&sh_B[(24 * 64 + l) * 8];
                #pragma unroll
                for (int m = 0; m < 4; ++m) {
                    const int mr = 4 * g + m;
                    bf16x8 Ah = __builtin_bit_cast(bf16x8, make_int4(0, 0, 0, 0));
                    if (o < 2) {
                        const int gy = yb + m + 1;
                        const int gx = x0 + wx + 1;
                        if (t > 0 && (u32)gy < (u32)HO && (u32)gx < (u32)WO)
                            Ah = *(const bf16x8*)&hr[((size_t)gy * WO + gx) * 16 + ci0];
                    } else if (o == 2) {
                        const u16* sp = &sx[mr * LCOLS + wx];
                        int4 p;
                        p.x = (int)((u32)sp[0]   | ((u32)sp[1]   << 16));
                        p.y = (int)((u32)sp[2]   | ((u32)sp[66]  << 16));
                        p.z = (int)((u32)sp[67]  | ((u32)sp[68]  << 16));
                        p.w = (int)((u32)sp[132] | ((u32)sp[133] << 16));
                        Ah = __builtin_bit_cast(bf16x8, p);
                    } else {
                        Ah = __builtin_bit_cast(bf16x8,
                              make_int4((int)(u32)sx[(mr + 2) * LCOLS + wx + 2], 0, 0, 0));
                    }
                    acc[m][0] = __builtin_amdgcn_mfma_f32_16x16x32_bf16(Ah, Bh0, acc[m][0], 0, 0, 0);
                    acc[m][1] = __builtin_amdgcn_mfma_f32_16x16x32_bf16(Ah, Bh1, acc[m][1], 0, 0, 0);
                    acc[m][2] = __builtin_amdgcn_mfma_f32_16x16x32_bf16(Ah, Bh2, acc[m][2], 0, 0, 0);
                    acc[m][2] = __builtin_amdgcn_mfma_f32_16x16x32_bf16(Ah, Bl2, acc[m][2], 0, 0, 0);
                    acc[m][3] = __builtin_amdgcn_mfma_f32_16x16x32_bf16(Ah, Bh3, acc[m][3], 0, 0, 0);
                }
            }
            // epilogue: gates + c update (regs) + h store. C layout: col=l&15, row=(l>>4)*4+r.
            #pragma unroll
            for (int m = 0; m < 4; ++m) {
                const int y = yb + m;
                if (y < HO) {
                    #pragma unroll
                    for (int r = 0; r < 4; ++r) {
                        const int x = x0 + wv_ * 16 + o * 4 + r;
                        if (x < WO) {
                            float cv = c_reg[g][m][r];
                            float zi = acc[m][0][r], zf = acc[m][1][r];
                            float zc = acc[m][2][r], zo = acc[m][3][r];
                            float cn = fmaf(hsg(zf), cv, hsg(zi) * tanh_fast(zc));
                            c_reg[g][m][r] = cn;
                            float hn = hsg(zo) * tanh_fast(cn);
                            hw[((size_t)y * WO + x) * 16 + ch] = f2bf(hn);
                        }
                    }
                }
            }
        }

        if (t + 1 < T_) {
            // prefetch x_{t+1} (block-local, before the global barrier)
            const u16* xs = xpb + (size_t)(b * T_ + t + 1) * HP * WP;
            u16* xd = sxr[(t + 1) & 1];
            for (int i = tid; i < LROWS * LCOLS; i += 256) {
                int ry = i / LCOLS, rx = i % LCOLS;
                int gy = y0 + ry, gx = x0 + rx;
                xd[i] = (gy < HP && gx < WP) ? xs[(size_t)gy * WP + gx] : (u16)0;
            }
            grid_barrier(bar, (u32)NBLK * (u32)(t + 1), tid);
        }
    }
}

// ---------------- dense ----------------
#define NPX    (HO * WO)                       // 75,684 pixels
#define PCHUNK 512
#define NCHUNK ((NPX + PCHUNK - 1) / PCHUNK)   // 148

__device__ __forceinline__ float dot2(u32 a, float w0, float w1, float s) {
    s = fmaf(bf2f((u16)a), w0, s);
    return fmaf(bf2f((u16)(a >> 16)), w1, s);
}

__global__ void dense1(const u16* __restrict__ h, const float* __restrict__ w,
                       float* __restrict__ partial) {
    int b = blockIdx.y, tid = threadIdx.x;
    const u16* hb = h + (size_t)b * NPX * 16;
    float s = 0.0f;
    #pragma unroll
    for (int pp = 0; pp < 2; ++pp) {
        int px = blockIdx.x * PCHUNK + tid * 2 + pp;
        if (px < NPX) {
            const int4* g = (const int4*)&hb[(size_t)px * 16];
            int4 a0 = g[0], a1 = g[1];
            const float* wp = &w[(size_t)px * 16];
            s = dot2((u32)a0.x, wp[0],  wp[1],  s);
            s = dot2((u32)a0.y, wp[2],  wp[3],  s);
            s = dot2((u32)a0.z, wp[4],  wp[5],  s);
            s = dot2((u32)a0.w, wp[6],  wp[7],  s);
            s = dot2((u32)a1.x, wp[8],  wp[9],  s);
            s = dot2((u32)a1.y, wp[10], wp[11], s);
            s = dot2((u32)a1.z, wp[12], wp[13], s);
            s = dot2((u32)a1.w, wp[14], wp[15], s);
        }
    }
    #pragma unroll
    for (int of = 32; of > 0; of >>= 1) s += __shfl_down(s, of, 64);
    __shared__ float red[4];
    if ((tid & 63) == 0) red[tid >> 6] = s;
    __syncthreads();
    if (tid == 0) partial[b * NCHUNK + blockIdx.x] = red[0] + red[1] + red[2] + red[3];
}

__global__ void dense2(const float* __restrict__ partial, const float* __restrict__ db,
                       float* __restrict__ out) {
    int b = blockIdx.x, tid = threadIdx.x;
    float s = 0.0f;
    for (int i = tid; i < NCHUNK; i += 256) s += partial[b * NCHUNK + i];
    #pragma unroll
    for (int of = 32; of > 0; of >>= 1) s += __shfl_down(s, of, 64);
    __shared__ float red[4];
    if ((tid & 63) == 0) red[tid >> 6] = s;
    __syncthreads();
    if (tid == 0) out[b] = red[0] + red[1] + red[2] + red[3] + db[0];
}

extern "C" void kernel_launch(void* const* d_in, const int* in_sizes, int n_in,
                              void* d_out, int out_size, void* d_ws, size_t ws_size,
                              hipStream_t stream) {
    const float* inputs = (const float*)d_in[0];
    const float* kin    = (const float*)d_in[1];
    const float* krec   = (const float*)d_in[2];
    const float* bias   = (const float*)d_in[3];
    const float* dw     = (const float*)d_in[4];
    const float* db     = (const float*)d_in[5];
    float* out = (float*)d_out;

    const size_t XPN = (size_t)B_ * T_ * HP * WP;   // 9,830,400 u16 (bf16 pooled x)
    const size_t HN  = (size_t)B_ * HO * WO * 16;   // 9,687,552 u16 per h buffer

    u16*   xp   = (u16*)d_ws;
    u16*   h0   = xp + XPN;
    u16*   h1   = h0 + HN;
    int4*  frag = (int4*)(h1 + HN);                 // 25,600 B
    float* part = (float*)(frag + NFRAG * 64);
    u32*   bar  = (u32*)(part + B_ * NCHUNK);

    hipMemsetAsync(bar, 0, sizeof(u32), stream);
    {
        int total = B_ * T_ * HP * (WP / 2);
        pool_kernel<<<(total + 255) / 256, 256, 0, stream>>>(inputs, (u32*)xp);
    }
    frag_build<<<(NFRAG * 64 + 255) / 256, 256, 0, stream>>>(krec, kin, frag);

    {
        dim3 cgrid(4, 16, 8);
        lstm_persist<<<cgrid, 256, 0, stream>>>(xp, h0, h1, frag, bias, bar);
    }
    // t=15 (odd) wrote h1
    dense1<<<dim3(NCHUNK, B_), 256, 0, stream>>>(h1, dw, part);
    dense2<<<B_, 256, 0, stream>>>(part, db, out);
}

// Round 7
// 2522.743 us; speedup vs baseline: 1.1667x; 1.1667x over previous
//
#include <hip/hip_runtime.h>
#include <hip/hip_bf16.h>
#include <cstdint>

#define B_  8
#define T_  16
#define HIN 640
#define WIN 480
#define HP  320
#define WP  240
#define HO  318
#define WO  238

typedef unsigned short u16;
typedef unsigned int   u32;
typedef __attribute__((ext_vector_type(8))) short bf16x8;
typedef __attribute__((ext_vector_type(4))) float f32x4;

#define NFRAG 25    // 20 hi (q0..4 x nt0..3) + 5 lo (nt=2 only, q0..4)
#define TROWS 20    // output rows per y-tile
#define RING  10    // h ring rows (reads {4g..4g+5}, writes {4g+6..4g+9}: disjoint mod 10)
#define PITCH 24    // halfwords per pixel slot (48 B, 16B-aligned, ~2-way banks)
#define LCOLS 66
#define XROWS 22
#define NBLK  512   // 2 blocks/CU x 256 CU; LDS 63 KB forces <=2/CU -> all resident

__device__ __forceinline__ u16 f2bf(float f) {          // RNE float->bf16 bits
    u32 u = __float_as_uint(f);
    return (u16)((u + 0x7fffu + ((u >> 16) & 1u)) >> 16);
}
__device__ __forceinline__ float bf2f(u16 u) {
    return __uint_as_float(((u32)u) << 16);
}
__device__ __forceinline__ float hsg(float v) {
    return fminf(fmaxf(fmaf(v, 0.2f, 0.5f), 0.0f), 1.0f);
}
// tanh = 1 - 2/(e^{2x}+1): exp overflow -> 1, exp(-inf) -> -1; no clamp needed
__device__ __forceinline__ float tanh_fast(float x) {
    float e = __expf(2.0f * x);
    return 1.0f - __fdividef(2.0f, e + 1.0f);
}

// ---------------- MaxPool (1,2,2) -> bf16 ----------------
__global__ void pool_kernel(const float* __restrict__ in, u32* __restrict__ out) {
    int idx = blockIdx.x * 256 + threadIdx.x;
    const int total = B_ * T_ * HP * (WP / 2);
    if (idx >= total) return;
    int xp   = idx % (WP / 2);
    int rest = idx / (WP / 2);
    int y    = rest % HP;
    int bt   = rest / HP;
    const float* src = in + ((size_t)bt * HIN + 2 * y) * WIN + xp * 4;
    float4 a = *(const float4*)src;
    float4 b = *(const float4*)(src + WIN);
    float m0 = fmaxf(fmaxf(a.x, a.y), fmaxf(b.x, b.y));
    float m1 = fmaxf(fmaxf(a.z, a.w), fmaxf(b.z, b.w));
    out[((size_t)bt * HP + y) * (WP / 2) + xp] = (u32)f2bf(m0) | ((u32)f2bf(m1) << 16);
}

// ---------------- weight fragment pre-pack ----------------
// K layout: k = tap*16+ci (k<144 recurrent), k = 144+xtap (k<153 input conv), else 0.
// Frags 0..19: hi plane, f = q*4+nt. Frags 20..24: lo plane of nt=2 (z_c gate), f = 20+q.
// B-frag (16x16x32): lane l holds W[k = q*32 + (l>>4)*8 + j][n = nt*16 + (l&15)], j=0..7.
__global__ void frag_build(const float* __restrict__ krec, const float* __restrict__ kin,
                           int4* __restrict__ fragbuf) {
    int idx = blockIdx.x * 256 + threadIdx.x;
    if (idx >= NFRAG * 64) return;
    int l = idx & 63, f = idx >> 6;
    int lo = (f >= 20);
    int q  = lo ? (f - 20) : (f >> 2);
    int nt = lo ? 2 : (f & 3);
    int n = nt * 16 + (l & 15), o = l >> 4;
    u16 u[8];
    #pragma unroll
    for (int j = 0; j < 8; ++j) {
        int k = q * 32 + o * 8 + j;
        float wv = 0.0f;
        if (k < 144) wv = krec[k * 64 + n];
        else if (k < 153) wv = kin[(k - 144) * 64 + n];
        u16 hi = f2bf(wv);
        u[j] = lo ? f2bf(wv - bf2f(hi)) : hi;
    }
    int4 v;
    v.x = (int)((u32)u[0] | ((u32)u[1] << 16));
    v.y = (int)((u32)u[2] | ((u32)u[3] << 16));
    v.z = (int)((u32)u[4] | ((u32)u[5] << 16));
    v.w = (int)((u32)u[6] | ((u32)u[7] << 16));
    fragbuf[f * 64 + l] = v;
}

// ---------------- device-scope grid barrier (monotone counter) ----------------
__device__ __forceinline__ void grid_barrier(u32* bar, u32 tgt, int tid) {
    __threadfence();             // release: h stores visible device-wide
    __syncthreads();
    if (tid == 0) {
        atomicAdd(bar, 1u);
        while (__hip_atomic_load(bar, __ATOMIC_RELAXED, __HIP_MEMORY_SCOPE_AGENT) < tgt)
            __builtin_amdgcn_s_sleep(2);
    }
    __syncthreads();
    __threadfence();             // acquire
}

// ---------------- persistent ConvLSTM: all 16 steps, c in regs, LDS-staged A ----------------
// Grid (4,16,8) = 512 blocks. Tile 64 x 20. LDS 63,088 B -> exactly 2 blocks/CU.
__global__ __launch_bounds__(256, 2)
void lstm_persist(const u16* __restrict__ xpb,
                  u16* __restrict__ hg0, u16* __restrict__ hg1,
                  const int4* __restrict__ fragbuf,
                  const float* __restrict__ bias,
                  u32* __restrict__ bar) {
    __shared__ __align__(16) u16 sh_h[RING * LCOLS * PITCH];   // 31,680 B
    __shared__ __align__(16) u16 sh_B[NFRAG * 64 * 8];         // 25,600 B
    __shared__ u16 sxr[2][XROWS * LCOLS];                      //  5,808 B

    const int tid = threadIdx.x;
    const int wv_ = tid >> 6;
    const int l   = tid & 63;
    const int x0  = blockIdx.x * 64;
    const int y0  = blockIdx.y * TROWS;
    const int b   = blockIdx.z;
    const int o   = l >> 4;
    const int ci0 = (o & 1) * 8;
    const int wx  = wv_ * 16 + (l & 15);
    const int ch  = l & 15;
    const size_t bb = (size_t)b * HO * WO * 16;

    for (int i = tid; i < NFRAG * 64; i += 256)
        ((int4*)sh_B)[i] = fragbuf[i];
    {
        const u16* xs = xpb + (size_t)(b * T_ + 0) * HP * WP;
        for (int i = tid; i < XROWS * LCOLS; i += 256) {
            int ry = i / LCOLS, rx = i % LCOLS;
            int gy = y0 + ry, gx = x0 + rx;
            sxr[0][i] = (gy < HP && gx < WP) ? xs[(size_t)gy * WP + gx] : (u16)0;
        }
    }
    float bv[4];
    #pragma unroll
    for (int nt = 0; nt < 4; ++nt) bv[nt] = bias[nt * 16 + ch];

    float c_reg[5][4][4];
    #pragma unroll
    for (int g = 0; g < 5; ++g)
        #pragma unroll
        for (int m = 0; m < 4; ++m)
            #pragma unroll
            for (int r = 0; r < 4; ++r) c_reg[g][m][r] = 0.0f;

    __syncthreads();

    #pragma unroll 1
    for (int t = 0; t < T_; ++t) {
        u16*       hw = ((t & 1) ? hg1 : hg0) + bb;
        const u16* hr = ((t & 1) ? hg0 : hg1) + bb;
        const u16* sx = sxr[t & 1];

        // stage h rows rel0..rel0+nr-1 (rel = gy-(y0-1)) into ring slot rel%10
        auto stage_h = [&](int rel0, int nr) {
            for (int i = tid; i < nr * 132; i += 256) {
                int r = i / 132, cc = i % 132;
                int px = cc >> 1, half = cc & 1;
                int rel = rel0 + r;
                int gy = y0 - 1 + rel, gx = x0 - 1 + px;
                int4 v = make_int4(0, 0, 0, 0);
                if (t > 0 && (u32)gy < (u32)HO && (u32)gx < (u32)WO)
                    v = *(const int4*)&hr[((size_t)gy * WO + gx) * 16 + half * 8];
                int slot = rel;
                if (slot >= RING) slot -= RING;
                if (slot >= RING) slot -= RING;
                *(int4*)&sh_h[(slot * LCOLS + px) * PITCH + half * 8] = v;
            }
        };

        stage_h(0, 6);   // rows for g=0

        #pragma unroll
        for (int g = 0; g < 5; ++g) {
            __syncthreads();              // stage(g) complete; compute(g-1) done everywhere
            if (g < 4) stage_h(4 * g + 6, 4);   // rows for g+1 (disjoint slots)

            f32x4 acc[4][4];
            #pragma unroll
            for (int m = 0; m < 4; ++m)
                #pragma unroll
                for (int nt = 0; nt < 4; ++nt)
                    acc[m][nt] = (f32x4){bv[nt], bv[nt], bv[nt], bv[nt]};

            if (t > 0) {
                // chunks 0..3: recurrent taps 0..7 (tap = 2q + lane-half)
                #pragma unroll 1
                for (int q = 0; q < 4; ++q) {
                    bf16x8 Bh0 = *(const bf16x8*)&sh_B[((q * 4 + 0) * 64 + l) * 8];
                    bf16x8 Bh1 = *(const bf16x8*)&sh_B[((q * 4 + 1) * 64 + l) * 8];
                    bf16x8 Bh2 = *(const bf16x8*)&sh_B[((q * 4 + 2) * 64 + l) * 8];
                    bf16x8 Bh3 = *(const bf16x8*)&sh_B[((q * 4 + 3) * 64 + l) * 8];
                    bf16x8 Bl2 = *(const bf16x8*)&sh_B[((20 + q) * 64 + l) * 8];
                    const int tap = 2 * q + (o >= 2 ? 1 : 0);
                    const int dy = tap / 3, dx = tap - 3 * dy;
                    #pragma unroll
                    for (int m = 0; m < 4; ++m) {
                        int rel = 4 * g + m + dy;
                        int slot = rel >= RING ? rel - RING : rel;
                        if (slot >= RING) slot -= RING;
                        bf16x8 Ah = *(const bf16x8*)&sh_h[(slot * LCOLS + wx + dx) * PITCH + ci0];
                        acc[m][0] = __builtin_amdgcn_mfma_f32_16x16x32_bf16(Ah, Bh0, acc[m][0], 0, 0, 0);
                        acc[m][1] = __builtin_amdgcn_mfma_f32_16x16x32_bf16(Ah, Bh1, acc[m][1], 0, 0, 0);
                        acc[m][2] = __builtin_amdgcn_mfma_f32_16x16x32_bf16(Ah, Bh2, acc[m][2], 0, 0, 0);
                        acc[m][2] = __builtin_amdgcn_mfma_f32_16x16x32_bf16(Ah, Bl2, acc[m][2], 0, 0, 0);
                        acc[m][3] = __builtin_amdgcn_mfma_f32_16x16x32_bf16(Ah, Bh3, acc[m][3], 0, 0, 0);
                    }
                }
            }
            // chunk 4: o=0,1 -> rec tap8 (ring holds zeros at t=0); o=2 -> x taps 0..7; o=3 -> x tap8
            {
                bf16x8 Bh0 = *(const bf16x8*)&sh_B[((16 + 0) * 64 + l) * 8];
                bf16x8 Bh1 = *(const bf16x8*)&sh_B[((16 + 1) * 64 + l) * 8];
                bf16x8 Bh2 = *(const bf16x8*)&sh_B[((16 + 2) * 64 + l) * 8];
                bf16x8 Bh3 = *(const bf16x8*)&sh_B[((16 + 3) * 64 + l) * 8];
                bf16x8 Bl2 = *(const bf16x8*)&sh_B[(24 * 64 + l) * 8];
                #pragma unroll
                for (int m = 0; m < 4; ++m) {
                    const int mr = 4 * g + m;
                    bf16x8 Ah;
                    if (o < 2) {
                        int rel = mr + 2;
                        int slot = rel >= RING ? rel - RING : rel;
                        if (slot >= RING) slot -= RING;
                        Ah = *(const bf16x8*)&sh_h[(slot * LCOLS + wx + 2) * PITCH + ci0];
                    } else if (o == 2) {
                        const u16* sp = &sx[mr * LCOLS + wx];
                        int4 p;
                        p.x = (int)((u32)sp[0]   | ((u32)sp[1]   << 16));
                        p.y = (int)((u32)sp[2]   | ((u32)sp[66]  << 16));
                        p.z = (int)((u32)sp[67]  | ((u32)sp[68]  << 16));
                        p.w = (int)((u32)sp[132] | ((u32)sp[133] << 16));
                        Ah = __builtin_bit_cast(bf16x8, p);
                    } else {
                        Ah = __builtin_bit_cast(bf16x8,
                              make_int4((int)(u32)sx[(mr + 2) * LCOLS + wx + 2], 0, 0, 0));
                    }
                    acc[m][0] = __builtin_amdgcn_mfma_f32_16x16x32_bf16(Ah, Bh0, acc[m][0], 0, 0, 0);
                    acc[m][1] = __builtin_amdgcn_mfma_f32_16x16x32_bf16(Ah, Bh1, acc[m][1], 0, 0, 0);
                    acc[m][2] = __builtin_amdgcn_mfma_f32_16x16x32_bf16(Ah, Bh2, acc[m][2], 0, 0, 0);
                    acc[m][2] = __builtin_amdgcn_mfma_f32_16x16x32_bf16(Ah, Bl2, acc[m][2], 0, 0, 0);
                    acc[m][3] = __builtin_amdgcn_mfma_f32_16x16x32_bf16(Ah, Bh3, acc[m][3], 0, 0, 0);
                }
            }
            // epilogue: gates + c update (regs) + h store. C layout: col=l&15, row=(l>>4)*4+r.
            #pragma unroll
            for (int m = 0; m < 4; ++m) {
                const int y = y0 + 4 * g + m;
                if (y < HO) {
                    #pragma unroll
                    for (int r = 0; r < 4; ++r) {
                        const int x = x0 + wv_ * 16 + o * 4 + r;
                        if (x < WO) {
                            float cv = c_reg[g][m][r];
                            float zi = acc[m][0][r], zf = acc[m][1][r];
                            float zc = acc[m][2][r], zo = acc[m][3][r];
                            float cn = fmaf(hsg(zf), cv, hsg(zi) * tanh_fast(zc));
                            c_reg[g][m][r] = cn;
                            float hn = hsg(zo) * tanh_fast(cn);
                            hw[((size_t)y * WO + x) * 16 + ch] = f2bf(hn);
                        }
                    }
                }
            }
        }

        if (t + 1 < T_) {
            // prefetch x_{t+1} into the other buffer (no conflict with this step's reads)
            const u16* xs = xpb + (size_t)(b * T_ + t + 1) * HP * WP;
            u16* xd = sxr[(t + 1) & 1];
            for (int i = tid; i < XROWS * LCOLS; i += 256) {
                int ry = i / LCOLS, rx = i % LCOLS;
                int gy = y0 + ry, gx = x0 + rx;
                xd[i] = (gy < HP && gx < WP) ? xs[(size_t)gy * WP + gx] : (u16)0;
            }
            grid_barrier(bar, (u32)NBLK * (u32)(t + 1), tid);
        }
    }
}

// ---------------- dense ----------------
#define NPX    (HO * WO)                       // 75,684 pixels
#define PCHUNK 512
#define NCHUNK ((NPX + PCHUNK - 1) / PCHUNK)   // 148

__device__ __forceinline__ float dot2(u32 a, float w0, float w1, float s) {
    s = fmaf(bf2f((u16)a), w0, s);
    return fmaf(bf2f((u16)(a >> 16)), w1, s);
}

__global__ void dense1(const u16* __restrict__ h, const float* __restrict__ w,
                       float* __restrict__ partial) {
    int b = blockIdx.y, tid = threadIdx.x;
    const u16* hb = h + (size_t)b * NPX * 16;
    float s = 0.0f;
    #pragma unroll
    for (int pp = 0; pp < 2; ++pp) {
        int px = blockIdx.x * PCHUNK + tid * 2 + pp;
        if (px < NPX) {
            const int4* g = (const int4*)&hb[(size_t)px * 16];
            int4 a0 = g[0], a1 = g[1];
            const float* wp = &w[(size_t)px * 16];
            s = dot2((u32)a0.x, wp[0],  wp[1],  s);
            s = dot2((u32)a0.y, wp[2],  wp[3],  s);
            s = dot2((u32)a0.z, wp[4],  wp[5],  s);
            s = dot2((u32)a0.w, wp[6],  wp[7],  s);
            s = dot2((u32)a1.x, wp[8],  wp[9],  s);
            s = dot2((u32)a1.y, wp[10], wp[11], s);
            s = dot2((u32)a1.z, wp[12], wp[13], s);
            s = dot2((u32)a1.w, wp[14], wp[15], s);
        }
    }
    #pragma unroll
    for (int of = 32; of > 0; of >>= 1) s += __shfl_down(s, of, 64);
    __shared__ float red[4];
    if ((tid & 63) == 0) red[tid >> 6] = s;
    __syncthreads();
    if (tid == 0) partial[b * NCHUNK + blockIdx.x] = red[0] + red[1] + red[2] + red[3];
}

__global__ void dense2(const float* __restrict__ partial, const float* __restrict__ db,
                       float* __restrict__ out) {
    int b = blockIdx.x, tid = threadIdx.x;
    float s = 0.0f;
    for (int i = tid; i < NCHUNK; i += 256) s += partial[b * NCHUNK + i];
    #pragma unroll
    for (int of = 32; of > 0; of >>= 1) s += __shfl_down(s, of, 64);
    __shared__ float red[4];
    if ((tid & 63) == 0) red[tid >> 6] = s;
    __syncthreads();
    if (tid == 0) out[b] = red[0] + red[1] + red[2] + red[3] + db[0];
}

extern "C" void kernel_launch(void* const* d_in, const int* in_sizes, int n_in,
                              void* d_out, int out_size, void* d_ws, size_t ws_size,
                              hipStream_t stream) {
    const float* inputs = (const float*)d_in[0];
    const float* kin    = (const float*)d_in[1];
    const float* krec   = (const float*)d_in[2];
    const float* bias   = (const float*)d_in[3];
    const float* dw     = (const float*)d_in[4];
    const float* db     = (const float*)d_in[5];
    float* out = (float*)d_out;

    const size_t XPN = (size_t)B_ * T_ * HP * WP;   // 9,830,400 u16 (bf16 pooled x)
    const size_t HN  = (size_t)B_ * HO * WO * 16;   // 9,687,552 u16 per h buffer

    u16*   xp   = (u16*)d_ws;
    u16*   h0   = xp + XPN;
    u16*   h1   = h0 + HN;
    int4*  frag = (int4*)(h1 + HN);                 // 25,600 B
    float* part = (float*)(frag + NFRAG * 64);
    u32*   bar  = (u32*)(part + B_ * NCHUNK);

    hipMemsetAsync(bar, 0, sizeof(u32), stream);
    {
        int total = B_ * T_ * HP * (WP / 2);
        pool_kernel<<<(total + 255) / 256, 256, 0, stream>>>(inputs, (u32*)xp);
    }
    frag_build<<<(NFRAG * 64 + 255) / 256, 256, 0, stream>>>(krec, kin, frag);

    {
        dim3 cgrid(4, 16, 8);
        lstm_persist<<<cgrid, 256, 0, stream>>>(xp, h0, h1, frag, bias, bar);
    }
    // t=15 (odd) wrote h1
    dense1<<<dim3(NCHUNK, B_), 256, 0, stream>>>(h1, dw, part);
    dense2<<<B_, 256, 0, stream>>>(part, db, out);
}

// Round 8
// 769.130 us; speedup vs baseline: 3.8268x; 3.2800x over previous
//
#include <hip/hip_runtime.h>
#include <hip/hip_bf16.h>
#include <cstdint>

#define B_  8
#define T_  16
#define HIN 640
#define WIN 480
#define HP  320
#define WP  240
#define HO  318
#define WO  238

typedef unsigned short u16;
typedef unsigned int   u32;
typedef __attribute__((ext_vector_type(8))) short bf16x8;
typedef __attribute__((ext_vector_type(4))) float f32x4;

#define TY    4
#define PITCH 24   // halfwords per pixel slot (48 B): b128-aligned, ~2-way banks
#define NFRAG 25   // 20 hi (q0..4 x nt0..3) + 5 lo (nt=2 only, q0..4)

__device__ __forceinline__ u16 f2bf(float f) {          // RNE float->bf16 bits
    u32 u = __float_as_uint(f);
    return (u16)((u + 0x7fffu + ((u >> 16) & 1u)) >> 16);
}
__device__ __forceinline__ float bf2f(u16 u) {
    return __uint_as_float(((u32)u) << 16);
}
__device__ __forceinline__ float h2f(u16 u) {           // fp16 bits -> f32
    _Float16 h = __builtin_bit_cast(_Float16, u);
    return (float)h;
}
__device__ __forceinline__ u16 f2h(float f) {           // f32 -> fp16 bits (RNE)
    _Float16 h = (_Float16)f;
    return __builtin_bit_cast(u16, h);
}
__device__ __forceinline__ float hsg(float v) {
    return fminf(fmaxf(fmaf(v, 0.2f, 0.5f), 0.0f), 1.0f);
}
// tanh = 1 - 2/(e^{2x}+1): exp overflow -> 1, exp(-inf) -> -1; no clamp needed
__device__ __forceinline__ float tanh_fast(float x) {
    float e = __expf(2.0f * x);
    return 1.0f - __fdividef(2.0f, e + 1.0f);
}

// ---------------- MaxPool (1,2,2) -> bf16 ----------------
__global__ void pool_kernel(const float* __restrict__ in, u32* __restrict__ out) {
    int idx = blockIdx.x * 256 + threadIdx.x;
    const int total = B_ * T_ * HP * (WP / 2);
    if (idx >= total) return;
    int xp   = idx % (WP / 2);
    int rest = idx / (WP / 2);
    int y    = rest % HP;
    int bt   = rest / HP;
    const float* src = in + ((size_t)bt * HIN + 2 * y) * WIN + xp * 4;
    float4 a = *(const float4*)src;
    float4 b = *(const float4*)(src + WIN);
    float m0 = fmaxf(fmaxf(a.x, a.y), fmaxf(b.x, b.y));
    float m1 = fmaxf(fmaxf(a.z, a.w), fmaxf(b.z, b.w));
    out[((size_t)bt * HP + y) * (WP / 2) + xp] = (u32)f2bf(m0) | ((u32)f2bf(m1) << 16);
}

// ---------------- weight fragment pre-pack ----------------
// K layout: k = tap*16+ci (k<144 recurrent), k = 144+xtap (k<153 input conv), else 0.
// Frags 0..19: hi plane, f = q*4+nt. Frags 20..24: lo plane of nt=2 (z_c gate), f = 20+q.
// B-frag (16x16x32): lane l holds W[k = q*32 + (l>>4)*8 + j][n = nt*16 + (l&15)], j=0..7.
__global__ void frag_build(const float* __restrict__ krec, const float* __restrict__ kin,
                           int4* __restrict__ fragbuf) {
    int idx = blockIdx.x * 256 + threadIdx.x;
    if (idx >= NFRAG * 64) return;
    int l = idx & 63, f = idx >> 6;
    int lo = (f >= 20);
    int q  = lo ? (f - 20) : (f >> 2);
    int nt = lo ? 2 : (f & 3);
    int n = nt * 16 + (l & 15), o = l >> 4;
    u16 u[8];
    #pragma unroll
    for (int j = 0; j < 8; ++j) {
        int k = q * 32 + o * 8 + j;
        float wv = 0.0f;
        if (k < 144) wv = krec[k * 64 + n];
        else if (k < 153) wv = kin[(k - 144) * 64 + n];
        u16 hi = f2bf(wv);
        u[j] = lo ? f2bf(wv - bf2f(hi)) : hi;
    }
    int4 v;
    v.x = (int)((u32)u[0] | ((u32)u[1] << 16));
    v.y = (int)((u32)u[2] | ((u32)u[3] << 16));
    v.z = (int)((u32)u[4] | ((u32)u[5] << 16));
    v.w = (int)((u32)u[6] | ((u32)u[7] << 16));
    fragbuf[f * 64 + l] = v;
}

// ---------------- fused ConvLSTM step ----------------
// Tile: TY=4 rows x 64 x. 4 waves; wave w owns x-slice w*16..+15, all rows, all 4 gates.
// z = h_bf16 * (w_hi + [nt==2] w_lo) + x_bf16 * (same); c carried in fp16.
__global__ __launch_bounds__(256, 3)
void lstm_step(const u16* __restrict__ xpb, int t,
               const u16* __restrict__ hin,    // [b][y][x][16] bf16
               u16* __restrict__ hout,
               u16* __restrict__ cbuf,         // [b][y][x][16] fp16
               const int4* __restrict__ fragbuf,
               const float* __restrict__ bias) {
    __shared__ __align__(16) u16 sh_h[6 * 66 * PITCH];   // 19,008 B
    __shared__ __align__(16) u16 sh_B[NFRAG * 64 * 8];   // 25,600 B
    __shared__ __align__(16) u16 sxf[2 * 256 * 8];       //  8,192 B  (total 52,800 B)

    const int tid = threadIdx.x;
    const int wv_ = tid >> 6;
    const int l   = tid & 63;
    const int b   = blockIdx.z;
    const int y0  = blockIdx.y * TY;
    const int x0  = blockIdx.x * 64;

    // stage B fragments (L2-hot)
    for (int i = tid; i < NFRAG * 64; i += 256)
        ((int4*)sh_B)[i] = fragbuf[i];
    // stage h halo (single bf16 plane, 32 B/pixel)
    for (int i = tid; i < 6 * 66; i += 256) {
        int hr = i / 66, hx = i % 66;
        int gy = y0 - 1 + hr, gx = x0 - 1 + hx;
        bool ok = (t > 0) && gy >= 0 && gy < HO && gx >= 0 && gx < WO;
        int4 v0 = make_int4(0, 0, 0, 0), v1 = v0;
        if (ok) {
            const int4* g = (const int4*)&hin[(((size_t)b * HO + gy) * WO + gx) * 16];
            v0 = g[0]; v1 = g[1];
        }
        u16* d = &sh_h[i * PITCH];
        *(int4*)d = v0; *(int4*)(d + 8) = v1;
    }
    // pack x A-fragments: slot tid = (m = tid>>6, sxi = tid&63). Taps 0..7 -> sxf[0], tap 8 -> sxf[1].
    {
        const int sxi = tid & 63, m = tid >> 6;
        const u16* xs = xpb + (size_t)(b * T_ + t) * HP * WP;
        u16 u[9];
        #pragma unroll
        for (int j = 0; j < 9; ++j) {
            int gy = y0 + m + j / 3, gx = x0 + sxi + j % 3;
            u[j] = (gy < HP && gx < WP) ? xs[(size_t)gy * WP + gx] : (u16)0;
        }
        int4 p;
        p.x = (int)((u32)u[0] | ((u32)u[1] << 16));
        p.y = (int)((u32)u[2] | ((u32)u[3] << 16));
        p.z = (int)((u32)u[4] | ((u32)u[5] << 16));
        p.w = (int)((u32)u[6] | ((u32)u[7] << 16));
        *(int4*)&sxf[tid * 8] = p;
        *(int4*)&sxf[(256 + tid) * 8] = make_int4((int)(u32)u[8], 0, 0, 0);
    }
    __syncthreads();

    float bv[4];
    #pragma unroll
    for (int nt = 0; nt < 4; ++nt) bv[nt] = bias[nt * 16 + (l & 15)];

    f32x4 acc[TY][4];
    #pragma unroll
    for (int m = 0; m < TY; ++m)
        #pragma unroll
        for (int nt = 0; nt < 4; ++nt)
            acc[m][nt] = (f32x4){bv[nt], bv[nt], bv[nt], bv[nt]};

    const int o    = l >> 4;
    const int ci0  = (o & 1) * 8;
    const bool hiH = (l >= 32);
    const int wx   = wv_ * 16 + (l & 15);

    // chunks 0..3: recurrent taps 0..7 (tap = 2q + lane-half)
    #pragma unroll 1
    for (int q = 0; q < 4; ++q) {
        bf16x8 Bh[4], Bl2;
        #pragma unroll
        for (int nt = 0; nt < 4; ++nt)
            Bh[nt] = *(const bf16x8*)&sh_B[((q * 4 + nt) * 64 + l) * 8];
        Bl2 = *(const bf16x8*)&sh_B[((20 + q) * 64 + l) * 8];
        const int tap = 2 * q + (hiH ? 1 : 0);
        const int dy = tap / 3, dx = tap - 3 * dy;
        #pragma unroll
        for (int m = 0; m < TY; ++m) {
            bf16x8 Ah = *(const bf16x8*)&sh_h[((m + dy) * 66 + wx + dx) * PITCH + ci0];
            acc[m][0] = __builtin_amdgcn_mfma_f32_16x16x32_bf16(Ah, Bh[0], acc[m][0], 0, 0, 0);
            acc[m][1] = __builtin_amdgcn_mfma_f32_16x16x32_bf16(Ah, Bh[1], acc[m][1], 0, 0, 0);
            acc[m][2] = __builtin_amdgcn_mfma_f32_16x16x32_bf16(Ah, Bh[2], acc[m][2], 0, 0, 0);
            acc[m][2] = __builtin_amdgcn_mfma_f32_16x16x32_bf16(Ah, Bl2,   acc[m][2], 0, 0, 0);
            acc[m][3] = __builtin_amdgcn_mfma_f32_16x16x32_bf16(Ah, Bh[3], acc[m][3], 0, 0, 0);
        }
    }
    // chunk 4: o=0,1 -> rec tap8 (ci 0..15); o=2 -> x taps 0..7; o=3 -> x tap8 + zeros
    {
        bf16x8 Bh[4], Bl2;
        #pragma unroll
        for (int nt = 0; nt < 4; ++nt)
            Bh[nt] = *(const bf16x8*)&sh_B[((16 + nt) * 64 + l) * 8];
        Bl2 = *(const bf16x8*)&sh_B[(24 * 64 + l) * 8];
        #pragma unroll
        for (int m = 0; m < TY; ++m) {
            bf16x8 Ah;
            if (!hiH) {
                Ah = *(const bf16x8*)&sh_h[((m + 2) * 66 + wx + 2) * PITCH + ci0];
            } else {
                const int slot = (o == 2 ? 0 : 256) + m * 64 + wx;
                Ah = *(const bf16x8*)&sxf[slot * 8];
            }
            acc[m][0] = __builtin_amdgcn_mfma_f32_16x16x32_bf16(Ah, Bh[0], acc[m][0], 0, 0, 0);
            acc[m][1] = __builtin_amdgcn_mfma_f32_16x16x32_bf16(Ah, Bh[1], acc[m][1], 0, 0, 0);
            acc[m][2] = __builtin_amdgcn_mfma_f32_16x16x32_bf16(Ah, Bh[2], acc[m][2], 0, 0, 0);
            acc[m][2] = __builtin_amdgcn_mfma_f32_16x16x32_bf16(Ah, Bl2,   acc[m][2], 0, 0, 0);
            acc[m][3] = __builtin_amdgcn_mfma_f32_16x16x32_bf16(Ah, Bh[3], acc[m][3], 0, 0, 0);
        }
    }

    // gates + state update. C layout: col = l&15 (channel), row = (l>>4)*4 + r (x offset).
    const int ch = l & 15;
    #pragma unroll
    for (int m = 0; m < TY; ++m) {
        const int y = y0 + m;
        if (y < HO) {
            #pragma unroll
            for (int r = 0; r < 4; ++r) {
                const int x = x0 + wv_ * 16 + (l >> 4) * 4 + r;
                if (x < WO) {
                    size_t px = ((size_t)b * HO + y) * WO + x;
                    size_t gc = px * 16 + ch;
                    float co = (t > 0) ? h2f(cbuf[gc]) : 0.0f;
                    float zi = acc[m][0][r], zf = acc[m][1][r], zc = acc[m][2][r], zo = acc[m][3][r];
                    float cn = fmaf(hsg(zf), co, hsg(zi) * tanh_fast(zc));
                    float hn = hsg(zo) * tanh_fast(cn);
                    cbuf[gc] = f2h(cn);
                    hout[gc] = f2bf(hn);
                }
            }
        }
    }
}

// ---------------- dense ----------------
#define NPX    (HO * WO)                       // 75,684 pixels
#define PCHUNK 512
#define NCHUNK ((NPX + PCHUNK - 1) / PCHUNK)   // 148

__device__ __forceinline__ float dot2(u32 a, float w0, float w1, float s) {
    s = fmaf(bf2f((u16)a), w0, s);
    return fmaf(bf2f((u16)(a >> 16)), w1, s);
}

__global__ void dense1(const u16* __restrict__ h, const float* __restrict__ w,
                       float* __restrict__ partial) {
    int b = blockIdx.y, tid = threadIdx.x;
    const u16* hb = h + (size_t)b * NPX * 16;
    float s = 0.0f;
    #pragma unroll
    for (int pp = 0; pp < 2; ++pp) {
        int px = blockIdx.x * PCHUNK + tid * 2 + pp;
        if (px < NPX) {
            const int4* g = (const int4*)&hb[(size_t)px * 16];
            int4 a0 = g[0], a1 = g[1];
            const float* wp = &w[(size_t)px * 16];
            s = dot2((u32)a0.x, wp[0],  wp[1],  s);
            s = dot2((u32)a0.y, wp[2],  wp[3],  s);
            s = dot2((u32)a0.z, wp[4],  wp[5],  s);
            s = dot2((u32)a0.w, wp[6],  wp[7],  s);
            s = dot2((u32)a1.x, wp[8],  wp[9],  s);
            s = dot2((u32)a1.y, wp[10], wp[11], s);
            s = dot2((u32)a1.z, wp[12], wp[13], s);
            s = dot2((u32)a1.w, wp[14], wp[15], s);
        }
    }
    #pragma unroll
    for (int of = 32; of > 0; of >>= 1) s += __shfl_down(s, of, 64);
    __shared__ float red[4];
    if ((tid & 63) == 0) red[tid >> 6] = s;
    __syncthreads();
    if (tid == 0) partial[b * NCHUNK + blockIdx.x] = red[0] + red[1] + red[2] + red[3];
}

__global__ void dense2(const float* __restrict__ partial, const float* __restrict__ db,
                       float* __restrict__ out) {
    int b = blockIdx.x, tid = threadIdx.x;
    float s = 0.0f;
    for (int i = tid; i < NCHUNK; i += 256) s += partial[b * NCHUNK + i];
    #pragma unroll
    for (int of = 32; of > 0; of >>= 1) s += __shfl_down(s, of, 64);
    __shared__ float red[4];
    if ((tid & 63) == 0) red[tid >> 6] = s;
    __syncthreads();
    if (tid == 0) out[b] = red[0] + red[1] + red[2] + red[3] + db[0];
}

extern "C" void kernel_launch(void* const* d_in, const int* in_sizes, int n_in,
                              void* d_out, int out_size, void* d_ws, size_t ws_size,
                              hipStream_t stream) {
    const float* inputs = (const float*)d_in[0];
    const float* kin    = (const float*)d_in[1];
    const float* krec   = (const float*)d_in[2];
    const float* bias   = (const float*)d_in[3];
    const float* dw     = (const float*)d_in[4];
    const float* db     = (const float*)d_in[5];
    float* out = (float*)d_out;

    const size_t XPN = (size_t)B_ * T_ * HP * WP;   // 9,830,400 u16 (bf16 pooled x)
    const size_t HN  = (size_t)B_ * HO * WO * 16;   // 9,687,552 u16 per h buffer

    u16*   xp   = (u16*)d_ws;
    u16*   h0   = xp + XPN;
    u16*   h1   = h0 + HN;
    u16*   cbuf = h1 + HN;                          // fp16 c state
    int4*  frag = (int4*)(cbuf + HN);               // 25,600 B
    float* part = (float*)(frag + NFRAG * 64);

    {
        int total = B_ * T_ * HP * (WP / 2);
        pool_kernel<<<(total + 255) / 256, 256, 0, stream>>>(inputs, (u32*)xp);
    }
    frag_build<<<(NFRAG * 64 + 255) / 256, 256, 0, stream>>>(krec, kin, frag);

    dim3 grid(4, (HO + TY - 1) / TY, B_);   // 4 x 80 x 8
    for (int t = 0; t < T_; ++t) {
        const u16* hi = (t & 1) ? h1 : h0;
        u16*       ho = (t & 1) ? h0 : h1;
        lstm_step<<<grid, 256, 0, stream>>>(xp, t, hi, ho, cbuf, frag, bias);
    }
    // t=15 (odd) wrote h0
    dense1<<<dim3(NCHUNK, B_), 256, 0, stream>>>(h0, dw, part);
    dense2<<<B_, 256, 0, stream>>>(part, db, out);
}

// Round 9
// 700.264 us; speedup vs baseline: 4.2032x; 1.0983x over previous
//
#include <hip/hip_runtime.h>
#include <hip/hip_bf16.h>
#include <cstdint>

#define B_  8
#define T_  16
#define HIN 640
#define WIN 480
#define HP  320
#define WP  240
#define HO  318
#define WO  238

typedef unsigned short u16;
typedef unsigned int   u32;
typedef __attribute__((ext_vector_type(8))) short bf16x8;
typedef __attribute__((ext_vector_type(4))) float f32x4;

#define TY    4
#define PITCH 24   // halfwords per pixel slot (48 B): b128-aligned, ~2-way banks
#define NFRAG 25   // 20 hi (q0..4 x nt0..3) + 5 lo (nt=2 only, q0..4)

__device__ __forceinline__ u16 f2bf(float f) {          // RNE float->bf16 bits
    u32 u = __float_as_uint(f);
    return (u16)((u + 0x7fffu + ((u >> 16) & 1u)) >> 16);
}
__device__ __forceinline__ float bf2f(u16 u) {
    return __uint_as_float(((u32)u) << 16);
}
__device__ __forceinline__ float h2f(u16 u) {           // fp16 bits -> f32
    _Float16 h = __builtin_bit_cast(_Float16, u);
    return (float)h;
}
__device__ __forceinline__ u16 f2h(float f) {           // f32 -> fp16 bits (RNE)
    _Float16 h = (_Float16)f;
    return __builtin_bit_cast(u16, h);
}
__device__ __forceinline__ float hsg(float v) {         // med3 clamp (2 instrs)
    return __builtin_amdgcn_fmed3f(fmaf(v, 0.2f, 0.5f), 0.0f, 1.0f);
}
// tanh = 1 - 2/(e^{2x}+1): exp overflow -> 1, exp(-inf) -> -1; no clamp needed
__device__ __forceinline__ float tanh_fast(float x) {
    float e = __expf(2.0f * x);
    return 1.0f - __fdividef(2.0f, e + 1.0f);
}

// ---------------- MaxPool (1,2,2) -> bf16 ----------------
__global__ void pool_kernel(const float* __restrict__ in, u32* __restrict__ out) {
    int idx = blockIdx.x * 256 + threadIdx.x;
    const int total = B_ * T_ * HP * (WP / 2);
    if (idx >= total) return;
    int xp   = idx % (WP / 2);
    int rest = idx / (WP / 2);
    int y    = rest % HP;
    int bt   = rest / HP;
    const float* src = in + ((size_t)bt * HIN + 2 * y) * WIN + xp * 4;
    float4 a = *(const float4*)src;
    float4 b = *(const float4*)(src + WIN);
    float m0 = fmaxf(fmaxf(a.x, a.y), fmaxf(b.x, b.y));
    float m1 = fmaxf(fmaxf(a.z, a.w), fmaxf(b.z, b.w));
    out[((size_t)bt * HP + y) * (WP / 2) + xp] = (u32)f2bf(m0) | ((u32)f2bf(m1) << 16);
}

// ---------------- weight fragment pre-pack ----------------
// K layout: k = tap*16+ci (k<144 recurrent), k = 144+xtap (k<153 input conv), else 0.
// Frags 0..19: hi plane, f = q*4+nt. Frags 20..24: lo plane of nt=2 (z_c gate), f = 20+q.
// B-frag (16x16x32): lane l holds W[k = q*32 + (l>>4)*8 + j][n = nt*16 + (l&15)], j=0..7.
__global__ void frag_build(const float* __restrict__ krec, const float* __restrict__ kin,
                           int4* __restrict__ fragbuf) {
    int idx = blockIdx.x * 256 + threadIdx.x;
    if (idx >= NFRAG * 64) return;
    int l = idx & 63, f = idx >> 6;
    int lo = (f >= 20);
    int q  = lo ? (f - 20) : (f >> 2);
    int nt = lo ? 2 : (f & 3);
    int n = nt * 16 + (l & 15), o = l >> 4;
    u16 u[8];
    #pragma unroll
    for (int j = 0; j < 8; ++j) {
        int k = q * 32 + o * 8 + j;
        float wv = 0.0f;
        if (k < 144) wv = krec[k * 64 + n];
        else if (k < 153) wv = kin[(k - 144) * 64 + n];
        u16 hi = f2bf(wv);
        u[j] = lo ? f2bf(wv - bf2f(hi)) : hi;
    }
    int4 v;
    v.x = (int)((u32)u[0] | ((u32)u[1] << 16));
    v.y = (int)((u32)u[2] | ((u32)u[3] << 16));
    v.z = (int)((u32)u[4] | ((u32)u[5] << 16));
    v.w = (int)((u32)u[6] | ((u32)u[7] << 16));
    fragbuf[f * 64 + l] = v;
}

// ---------------- fused ConvLSTM step ----------------
// Tile: TY=4 rows x 64 x. 4 waves; wave w owns x-slice w*16..+15, all rows, all 4 gates.
// B-fragments read straight from global (25.6 KB, L1-resident per CU) -> LDS only
// holds h halo + packed x frags (27.2 KB) -> 4 blocks/CU, 16 waves/CU.
__global__ __launch_bounds__(256, 4)
void lstm_step(const u16* __restrict__ xpb, int t,
               const u16* __restrict__ hin,    // [b][y][x][16] bf16
               u16* __restrict__ hout,
               u16* __restrict__ cbuf,         // [b][y][x][16] fp16
               const int4* __restrict__ fragbuf,
               const float* __restrict__ bias) {
    __shared__ __align__(16) u16 sh_h[6 * 66 * PITCH];   // 19,008 B
    __shared__ __align__(16) u16 sxf[2 * 256 * 8];       //  8,192 B  (total 27,200 B)

    const int tid = threadIdx.x;
    const int wv_ = tid >> 6;
    const int l   = tid & 63;
    const int b   = blockIdx.z;
    const int y0  = blockIdx.y * TY;
    const int x0  = blockIdx.x * 64;

    // stage h halo (single bf16 plane, 32 B/pixel)
    for (int i = tid; i < 6 * 66; i += 256) {
        int hr = i / 66, hx = i % 66;
        int gy = y0 - 1 + hr, gx = x0 - 1 + hx;
        bool ok = (t > 0) && gy >= 0 && gy < HO && gx >= 0 && gx < WO;
        int4 v0 = make_int4(0, 0, 0, 0), v1 = v0;
        if (ok) {
            const int4* g = (const int4*)&hin[(((size_t)b * HO + gy) * WO + gx) * 16];
            v0 = g[0]; v1 = g[1];
        }
        u16* d = &sh_h[i * PITCH];
        *(int4*)d = v0; *(int4*)(d + 8) = v1;
    }
    // pack x A-fragments: slot tid = (m = tid>>6, sxi = tid&63). Taps 0..7 -> sxf[0], tap 8 -> sxf[1].
    {
        const int sxi = tid & 63, m = tid >> 6;
        const u16* xs = xpb + (size_t)(b * T_ + t) * HP * WP;
        u16 u[9];
        #pragma unroll
        for (int j = 0; j < 9; ++j) {
            int gy = y0 + m + j / 3, gx = x0 + sxi + j % 3;
            u[j] = (gy < HP && gx < WP) ? xs[(size_t)gy * WP + gx] : (u16)0;
        }
        int4 p;
        p.x = (int)((u32)u[0] | ((u32)u[1] << 16));
        p.y = (int)((u32)u[2] | ((u32)u[3] << 16));
        p.z = (int)((u32)u[4] | ((u32)u[5] << 16));
        p.w = (int)((u32)u[6] | ((u32)u[7] << 16));
        *(int4*)&sxf[tid * 8] = p;
        *(int4*)&sxf[(256 + tid) * 8] = make_int4((int)(u32)u[8], 0, 0, 0);
    }
    __syncthreads();

    float bv[4];
    #pragma unroll
    for (int nt = 0; nt < 4; ++nt) bv[nt] = bias[nt * 16 + (l & 15)];

    f32x4 acc[TY][4];
    #pragma unroll
    for (int m = 0; m < TY; ++m)
        #pragma unroll
        for (int nt = 0; nt < 4; ++nt)
            acc[m][nt] = (f32x4){bv[nt], bv[nt], bv[nt], bv[nt]};

    const int o    = l >> 4;
    const int ci0  = (o & 1) * 8;
    const bool hiH = (l >= 32);
    const int wx   = wv_ * 16 + (l & 15);
    const int4* fbl = fragbuf + l;   // lane's record: fbl[f*64]

    // chunks 0..3: recurrent taps 0..7 (tap = 2q + lane-half). B from global (L1-hot).
    #pragma unroll 1
    for (int q = 0; q < 4; ++q) {
        bf16x8 Bh0 = __builtin_bit_cast(bf16x8, fbl[(q * 4 + 0) * 64]);
        bf16x8 Bh1 = __builtin_bit_cast(bf16x8, fbl[(q * 4 + 1) * 64]);
        bf16x8 Bh2 = __builtin_bit_cast(bf16x8, fbl[(q * 4 + 2) * 64]);
        bf16x8 Bh3 = __builtin_bit_cast(bf16x8, fbl[(q * 4 + 3) * 64]);
        bf16x8 Bl2 = __builtin_bit_cast(bf16x8, fbl[(20 + q) * 64]);
        const int tap = 2 * q + (hiH ? 1 : 0);
        const int dy = tap / 3, dx = tap - 3 * dy;
        #pragma unroll
        for (int m = 0; m < TY; ++m) {
            bf16x8 Ah = *(const bf16x8*)&sh_h[((m + dy) * 66 + wx + dx) * PITCH + ci0];
            acc[m][0] = __builtin_amdgcn_mfma_f32_16x16x32_bf16(Ah, Bh0, acc[m][0], 0, 0, 0);
            acc[m][1] = __builtin_amdgcn_mfma_f32_16x16x32_bf16(Ah, Bh1, acc[m][1], 0, 0, 0);
            acc[m][2] = __builtin_amdgcn_mfma_f32_16x16x32_bf16(Ah, Bh2, acc[m][2], 0, 0, 0);
            acc[m][2] = __builtin_amdgcn_mfma_f32_16x16x32_bf16(Ah, Bl2,  acc[m][2], 0, 0, 0);
            acc[m][3] = __builtin_amdgcn_mfma_f32_16x16x32_bf16(Ah, Bh3,  acc[m][3], 0, 0, 0);
        }
    }
    // chunk 4: o=0,1 -> rec tap8 (ci 0..15); o=2 -> x taps 0..7; o=3 -> x tap8 + zeros
    {
        bf16x8 Bh0 = __builtin_bit_cast(bf16x8, fbl[(16 + 0) * 64]);
        bf16x8 Bh1 = __builtin_bit_cast(bf16x8, fbl[(16 + 1) * 64]);
        bf16x8 Bh2 = __builtin_bit_cast(bf16x8, fbl[(16 + 2) * 64]);
        bf16x8 Bh3 = __builtin_bit_cast(bf16x8, fbl[(16 + 3) * 64]);
        bf16x8 Bl2 = __builtin_bit_cast(bf16x8, fbl[24 * 64]);
        #pragma unroll
        for (int m = 0; m < TY; ++m) {
            bf16x8 Ah;
            if (!hiH) {
                Ah = *(const bf16x8*)&sh_h[((m + 2) * 66 + wx + 2) * PITCH + ci0];
            } else {
                const int slot = (o == 2 ? 0 : 256) + m * 64 + wx;
                Ah = *(const bf16x8*)&sxf[slot * 8];
            }
            acc[m][0] = __builtin_amdgcn_mfma_f32_16x16x32_bf16(Ah, Bh0, acc[m][0], 0, 0, 0);
            acc[m][1] = __builtin_amdgcn_mfma_f32_16x16x32_bf16(Ah, Bh1, acc[m][1], 0, 0, 0);
            acc[m][2] = __builtin_amdgcn_mfma_f32_16x16x32_bf16(Ah, Bh2, acc[m][2], 0, 0, 0);
            acc[m][2] = __builtin_amdgcn_mfma_f32_16x16x32_bf16(Ah, Bl2,  acc[m][2], 0, 0, 0);
            acc[m][3] = __builtin_amdgcn_mfma_f32_16x16x32_bf16(Ah, Bh3,  acc[m][3], 0, 0, 0);
        }
    }

    // gates + state update. C layout: col = l&15 (channel), row = (l>>4)*4 + r (x offset).
    const int ch = l & 15;
    #pragma unroll
    for (int m = 0; m < TY; ++m) {
        const int y = y0 + m;
        if (y < HO) {
            #pragma unroll
            for (int r = 0; r < 4; ++r) {
                const int x = x0 + wv_ * 16 + (l >> 4) * 4 + r;
                if (x < WO) {
                    size_t px = ((size_t)b * HO + y) * WO + x;
                    size_t gc = px * 16 + ch;
                    float co = (t > 0) ? h2f(cbuf[gc]) : 0.0f;
                    float zi = acc[m][0][r], zf = acc[m][1][r], zc = acc[m][2][r], zo = acc[m][3][r];
                    float cn = fmaf(hsg(zf), co, hsg(zi) * tanh_fast(zc));
                    float hn = hsg(zo) * tanh_fast(cn);
                    cbuf[gc] = f2h(cn);
                    hout[gc] = f2bf(hn);
                }
            }
        }
    }
}

// ---------------- dense ----------------
#define NPX    (HO * WO)                       // 75,684 pixels
#define PCHUNK 512
#define NCHUNK ((NPX + PCHUNK - 1) / PCHUNK)   // 148

__device__ __forceinline__ float dot2(u32 a, float w0, float w1, float s) {
    s = fmaf(bf2f((u16)a), w0, s);
    return fmaf(bf2f((u16)(a >> 16)), w1, s);
}

__global__ void dense1(const u16* __restrict__ h, const float* __restrict__ w,
                       float* __restrict__ partial) {
    int b = blockIdx.y, tid = threadIdx.x;
    const u16* hb = h + (size_t)b * NPX * 16;
    float s = 0.0f;
    #pragma unroll
    for (int pp = 0; pp < 2; ++pp) {
        int px = blockIdx.x * PCHUNK + tid * 2 + pp;
        if (px < NPX) {
            const int4* g = (const int4*)&hb[(size_t)px * 16];
            int4 a0 = g[0], a1 = g[1];
            const float* wp = &w[(size_t)px * 16];
            s = dot2((u32)a0.x, wp[0],  wp[1],  s);
            s = dot2((u32)a0.y, wp[2],  wp[3],  s);
            s = dot2((u32)a0.z, wp[4],  wp[5],  s);
            s = dot2((u32)a0.w, wp[6],  wp[7],  s);
            s = dot2((u32)a1.x, wp[8],  wp[9],  s);
            s = dot2((u32)a1.y, wp[10], wp[11], s);
            s = dot2((u32)a1.z, wp[12], wp[13], s);
            s = dot2((u32)a1.w, wp[14], wp[15], s);
        }
    }
    #pragma unroll
    for (int of = 32; of > 0; of >>= 1) s += __shfl_down(s, of, 64);
    __shared__ float red[4];
    if ((tid & 63) == 0) red[tid >> 6] = s;
    __syncthreads();
    if (tid == 0) partial[b * NCHUNK + blockIdx.x] = red[0] + red[1] + red[2] + red[3];
}

__global__ void dense2(const float* __restrict__ partial, const float* __restrict__ db,
                       float* __restrict__ out) {
    int b = blockIdx.x, tid = threadIdx.x;
    float s = 0.0f;
    for (int i = tid; i < NCHUNK; i += 256) s += partial[b * NCHUNK + i];
    #pragma unroll
    for (int of = 32; of > 0; of >>= 1) s += __shfl_down(s, of, 64);
    __shared__ float red[4];
    if ((tid & 63) == 0) red[tid >> 6] = s;
    __syncthreads();
    if (tid == 0) out[b] = red[0] + red[1] + red[2] + red[3] + db[0];
}

extern "C" void kernel_launch(void* const* d_in, const int* in_sizes, int n_in,
                              void* d_out, int out_size, void* d_ws, size_t ws_size,
                              hipStream_t stream) {
    const float* inputs = (const float*)d_in[0];
    const float* kin    = (const float*)d_in[1];
    const float* krec   = (const float*)d_in[2];
    const float* bias   = (const float*)d_in[3];
    const float* dw     = (const float*)d_in[4];
    const float* db     = (const float*)d_in[5];
    float* out = (float*)d_out;

    const size_t XPN = (size_t)B_ * T_ * HP * WP;   // 9,830,400 u16 (bf16 pooled x)
    const size_t HN  = (size_t)B_ * HO * WO * 16;   // 9,687,552 u16 per h buffer

    u16*   xp   = (u16*)d_ws;
    u16*   h0   = xp + XPN;
    u16*   h1   = h0 + HN;
    u16*   cbuf = h1 + HN;                          // fp16 c state
    int4*  frag = (int4*)(cbuf + HN);               // 25,600 B
    float* part = (float*)(frag + NFRAG * 64);

    {
        int total = B_ * T_ * HP * (WP / 2);
        pool_kernel<<<(total + 255) / 256, 256, 0, stream>>>(inputs, (u32*)xp);
    }
    frag_build<<<(NFRAG * 64 + 255) / 256, 256, 0, stream>>>(krec, kin, frag);

    dim3 grid(4, (HO + TY - 1) / TY, B_);   // 4 x 80 x 8
    for (int t = 0; t < T_; ++t) {
        const u16* hi = (t & 1) ? h1 : h0;
        u16*       ho = (t & 1) ? h0 : h1;
        lstm_step<<<grid, 256, 0, stream>>>(xp, t, hi, ho, cbuf, frag, bias);
    }
    // t=15 (odd) wrote h0
    dense1<<<dim3(NCHUNK, B_), 256, 0, stream>>>(h0, dw, part);
    dense2<<<B_, 256, 0, stream>>>(part, db, out);
}